// Round 3
// baseline (442.709 us; speedup 1.0000x reference)
//
#include <hip/hip_runtime.h>

// SimpleScheduler fused kernel for MI355X (gfx950).
// B=16384, D=4096, H=32, P=16, S=16, NH=32, TAU=5, NEG=-1e9.
//
// One block = 512 threads (8 waves) handles 64 rows of x.
//   Phase 1: logits = x@W + b. Lane-owns-row; K split 8-way across waves
//            (512 k each). x staged through PER-WAVE private LDS tiles
//            [64][33] (pad +1 => 2 lanes/bank, conflict-free) -- no block
//            barriers needed (same-wave LDS RAW only), register
//            double-buffered prefetch. W read at wave-uniform addresses
//            (s_load broadcast, L2-resident). 4 sub-accumulators/lane keep
//            fp32 rounding ~XLA-like to protect downstream argmax decisions.
//   Phase 2: deterministic 8-way partial reduction in LDS (+bias).
//   Phase 3: wave 0 (lane-per-row): n = clip(round(lat*32),16,32)-16 draws of
//            gumbel-softmax argmax WITHOUT replacement, mimicking reference fp
//            arithmetic exactly (div by 5.0, max-sub, expf, e/sum, first-index
//            argmax). Meanwhile waves 1-7 stream the prefix all-ones half of
//            the output (mask-independent).
//   Phase 4: all 8 waves stream the mask half, fully coalesced 16B nt stores.
// LDS overlaid: 8x2112 floats (66 KB) for tiles, reused for red/logits/selb.

#define BB 16384
#define DD 4096

typedef float f32x4 __attribute__((ext_vector_type(4)));

__global__ __launch_bounds__(512, 2) void simple_scheduler_kernel(
    const float* __restrict__ x, const float* __restrict__ lat,
    const float* __restrict__ W, const float* __restrict__ bh,
    const float* __restrict__ gum, float* __restrict__ out) {
  __shared__ float smem[8 * 2112];  // 67584 B

  const int t = threadIdx.x;
  const int lane = t & 63;
  const int wid = __builtin_amdgcn_readfirstlane(t >> 6);  // wave-uniform
  const int rb = blockIdx.x * 64;

  // ---------------- Phase 1: GEMM partials (per-wave, barrier-free) --------
  float a0[16], a1[16], a2[16], a3[16];
#pragma unroll
  for (int j = 0; j < 16; ++j) { a0[j] = 0.f; a1[j] = 0.f; a2[j] = 0.f; a3[j] = 0.f; }

  const int k0 = wid * 512;             // this wave's K range
  float* tile = smem + wid * 2112;      // private [64][33]
  const int r8 = lane >> 3;             // staging row group 0..7
  const int c4 = (lane & 7) * 4;        // float4 column
  const int lrow = lane * 33;
  const float* xbase = x + (size_t)(rb + r8) * DD + k0 + c4;

  f32x4 v[8];
#pragma unroll
  for (int rr = 0; rr < 8; ++rr)
    v[rr] = __builtin_nontemporal_load(
        reinterpret_cast<const f32x4*>(xbase + (size_t)rr * 8 * DD));

  for (int s = 0; s < 16; ++s) {        // 16 stages x 32 k
    const int kc = k0 + s * 32;
#pragma unroll
    for (int rr = 0; rr < 8; ++rr) {
      const int o = (r8 + rr * 8) * 33 + c4;
      tile[o] = v[rr].x; tile[o + 1] = v[rr].y;
      tile[o + 2] = v[rr].z; tile[o + 3] = v[rr].w;
    }
    if (s < 15) {                       // prefetch next stage (overlaps FMA)
      const float* xn = xbase + (s + 1) * 32;
#pragma unroll
      for (int rr = 0; rr < 8; ++rr)
        v[rr] = __builtin_nontemporal_load(
            reinterpret_cast<const f32x4*>(xn + (size_t)rr * 8 * DD));
    }
#pragma unroll
    for (int i = 0; i < 32; i += 4) {
      const float x0 = tile[lrow + i];
      const float x1 = tile[lrow + i + 1];
      const float x2 = tile[lrow + i + 2];
      const float x3 = tile[lrow + i + 3];
      const float* w0 = W + (size_t)(kc + i) * 16;  // wave-uniform -> s_load
#pragma unroll
      for (int j = 0; j < 16; ++j) {
        a0[j] = fmaf(w0[j],      x0, a0[j]);
        a1[j] = fmaf(w0[16 + j], x1, a1[j]);
        a2[j] = fmaf(w0[32 + j], x2, a2[j]);
        a3[j] = fmaf(w0[48 + j], x3, a3[j]);
      }
    }
    // no __syncthreads: tile is wave-private; LDS pipe orders same-wave ops
  }

  __syncthreads();                      // all waves done with tiles -> overlay
  float* red    = smem;                 // [8][64*17]  (8704 floats)
  float* logitl = smem + 8704;          // [64*17]
  float* selb   = smem + 9792;          // [64*17]

#pragma unroll
  for (int j = 0; j < 16; ++j)
    red[wid * 1088 + lane * 17 + j] = (a0[j] + a1[j]) + (a2[j] + a3[j]);
  __syncthreads();

  // ---------------- Phase 2: combine partials (deterministic order) --------
  {
    int p = t;
#pragma unroll
    for (int rep = 0; rep < 2; ++rep, p += 512) {
      const int row = p >> 4, j = p & 15;
      float ssum = 0.f;
#pragma unroll
      for (int w = 0; w < 8; ++w) ssum += red[w * 1088 + row * 17 + j];
      logitl[row * 17 + j] = ssum + bh[j];
    }
  }
  __syncthreads();

  f32x4* op = reinterpret_cast<f32x4*>(out + (size_t)rb * 2048);

  if (t >= 64) {
    // -------- waves 1-7: prefix ones half (cols 0..255 per row) ------------
    const f32x4 ones = {1.f, 1.f, 1.f, 1.f};
    for (int i = t - 64; i < 64 * 256; i += 448) {
      const int row = i >> 8, col = i & 255;
      __builtin_nontemporal_store(ones, &op[(size_t)row * 512 + col]);
    }
  } else {
    // -------- wave 0: gumbel top-n without replacement ---------------------
    const int row = rb + lane;
    float lg[16];
#pragma unroll
    for (int j = 0; j < 16; ++j) lg[j] = logitl[lane * 17 + j];

    float nf = rintf(lat[row] * 32.0f);       // round-half-even = jnp.round
    nf = fminf(fmaxf(nf, 16.0f), 32.0f);
    const int n = (int)nf - 16;               // 0..16 draws

    int nmax = n;
#pragma unroll
    for (int o = 32; o > 0; o >>= 1) nmax = max(nmax, __shfl_xor(nmax, o));

    unsigned sel = 0u;
    for (int tt = 0; tt < nmax; ++tt) {
      if (tt < n) {
        const float* gp = gum + ((size_t)tt * BB + row) * 16;
        const f32x4 g0 = reinterpret_cast<const f32x4*>(gp)[0];
        const f32x4 g1 = reinterpret_cast<const f32x4*>(gp)[1];
        const f32x4 g2 = reinterpret_cast<const f32x4*>(gp)[2];
        const f32x4 g3 = reinterpret_cast<const f32x4*>(gp)[3];
        const float gv[16] = {g0.x, g0.y, g0.z, g0.w, g1.x, g1.y, g1.z, g1.w,
                              g2.x, g2.y, g2.z, g2.w, g3.x, g3.y, g3.z, g3.w};
        float av[16];
#pragma unroll
        for (int j = 0; j < 16; ++j) {
          const float masked = lg[j] + (((sel >> j) & 1u) ? -1e9f : 0.0f);
          av[j] = (masked + gv[j]) / 5.0f;    // IEEE divide, matches reference
        }
        float m = av[0];
#pragma unroll
        for (int j = 1; j < 16; ++j) m = fmaxf(m, av[j]);
        float ev[16];
        float se = 0.f;
#pragma unroll
        for (int j = 0; j < 16; ++j) { ev[j] = expf(av[j] - m); se += ev[j]; }
        float pm = ev[0] / se;                // softmax value, like reference
        int jm = 0;
#pragma unroll
        for (int j = 1; j < 16; ++j) {
          const float pj = ev[j] / se;
          if (pj > pm) { pm = pj; jm = j; }   // strict > = first-index argmax
        }
        sel |= 1u << jm;
      }
    }
#pragma unroll
    for (int j = 0; j < 16; ++j)
      selb[lane * 17 + j] = ((sel >> j) & 1u) ? 1.0f : 0.0f;
  }
  __syncthreads();

  // ---------------- Phase 4: mask half (cols 256..511 per row) -------------
  for (int i = t; i < 64 * 256; i += 512) {
    const int row = i >> 8, c = i & 255;
    const float vv = selb[row * 17 + (c >> 4)];
    const f32x4 vvv = {vv, vv, vv, vv};
    __builtin_nontemporal_store(vvv, &op[(size_t)row * 512 + 256 + c]);
  }
}

extern "C" void kernel_launch(void* const* d_in, const int* in_sizes, int n_in,
                              void* d_out, int out_size, void* d_ws, size_t ws_size,
                              hipStream_t stream) {
  const float* x   = (const float*)d_in[0];   // [B, D]
  const float* lat = (const float*)d_in[1];   // [B]
  const float* W   = (const float*)d_in[2];   // [D, 16]
  const float* bh  = (const float*)d_in[3];   // [16]
  const float* gum = (const float*)d_in[4];   // [16, B, 16]
  float* out = (float*)d_out;                 // [B, 32, 2, 32]

  const int B = in_sizes[1];                  // 16384
  simple_scheduler_kernel<<<B / 64, 512, 0, stream>>>(x, lat, W, bh, gum, out);
}